// Round 2
// baseline (417.448 us; speedup 1.0000x reference)
//
#include <hip/hip_runtime.h>

// Embedding gather: out[b,t,:] = W[:, tokens[b,t]] + bias
//   tokens: [8, 2048] int32
//   W:      [768, 50257] float32 (row-major: W[e*V + v])
//   bias:   [768] float32
//   out:    [8, 2048, 768] float32
//
// Memory-bound gather. Output writes are coalesced float4 (4 consecutive e
// per thread). W reads are inherently strided (column gather, stride V*4B);
// the 256MB L3 caches all of W (154MB) so HBM read traffic ~= |W| once.

constexpr int VOCAB = 50257;
constexpr int EMBED = 768;
constexpr int NTOK  = 8 * 2048;
constexpr int E4    = EMBED / 4;          // 192 float4 groups per token
constexpr int TOTAL = NTOK * E4;          // threads needed

typedef float f32x4 __attribute__((ext_vector_type(4)));  // true vector type for nontemporal store

__global__ __launch_bounds__(256) void embed_gather_kernel(
    const int*   __restrict__ tokens,
    const float* __restrict__ W,
    const float* __restrict__ bias,
    float*       __restrict__ out)
{
    int idx = blockIdx.x * blockDim.x + threadIdx.x;
    if (idx >= TOTAL) return;

    int t  = idx / E4;              // which token
    int e4 = (idx - t * E4) * 4;    // first of 4 embedding dims

    int tok = tokens[t];            // L1/L2 broadcast across the 192 threads of this token

    const float* wp = W + (size_t)e4 * VOCAB + tok;
    f32x4 r;
    r.x = wp[0 * (size_t)VOCAB] + bias[e4 + 0];
    r.y = wp[1 * (size_t)VOCAB] + bias[e4 + 1];
    r.z = wp[2 * (size_t)VOCAB] + bias[e4 + 2];
    r.w = wp[3 * (size_t)VOCAB] + bias[e4 + 3];

    // Nontemporal: output is write-once, keep L2 for W lines.
    __builtin_nontemporal_store(r, reinterpret_cast<f32x4*>(out) + idx);
}

extern "C" void kernel_launch(void* const* d_in, const int* in_sizes, int n_in,
                              void* d_out, int out_size, void* d_ws, size_t ws_size,
                              hipStream_t stream) {
    const int*   tokens = (const int*)  d_in[0];
    const float* W      = (const float*)d_in[1];
    const float* bias   = (const float*)d_in[2];
    float*       out    = (float*)      d_out;

    constexpr int BLOCK = 256;
    constexpr int GRID  = (TOTAL + BLOCK - 1) / BLOCK;   // 12288 blocks
    embed_gather_kernel<<<GRID, BLOCK, 0, stream>>>(tokens, W, bias, out);
}

// Round 3
// 274.764 us; speedup vs baseline: 1.5193x; 1.5193x over previous
//
#include <hip/hip_runtime.h>

// Embedding gather: out[b,t,:] = W[:, tokens[b,t]] + bias
//   tokens: [16384] int32, W: [768, 50257] f32 row-major, bias: [768], out: [16384, 768]
//
// Round-2 lesson: arrival-order gather fetched 766 MB (5x the 154 MB distinct-line
// footprint of W) because tokens sharing a W cache line were scattered across
// XCDs/time. Fix: counting-sort tokens by vocab bucket (tok>>4) so same-line
// tokens are processed by adjacent blocks, + XCD-chunked swizzle so adjacent
// blocks share an L2. Per-XCD reuse window ~3.2 MB < 4 MB L2.
//
// ws layout (int32): [0,4096) bucket counters -> exclusive offsets -> scatter cursor
//                    [4096, 4096+16384) packed pairs (t<<16 | tok), vocab-sorted

constexpr int V     = 50257;
constexpr int E     = 768;
constexpr int NTOK  = 8 * 2048;          // 16384
constexpr int NB    = (V + 15) / 16;     // 3142 buckets of 16 vocab entries
constexpr int NBP   = 4096;              // padded bucket count (zeros beyond NB)

typedef float f32x4 __attribute__((ext_vector_type(4)));

// --- K2: histogram tokens into buckets (cnt must be pre-zeroed) ---
__global__ __launch_bounds__(256) void hist_kernel(const int* __restrict__ tokens,
                                                   int* __restrict__ cnt) {
    int t = blockIdx.x * 256 + threadIdx.x;
    atomicAdd(&cnt[tokens[t] >> 4], 1);
}

// --- K3: exclusive prefix scan of cnt[4096] in-place, single wave ---
__global__ __launch_bounds__(64) void scan_kernel(int* __restrict__ cnt) {
    int lane = threadIdx.x;
    int v[64];
    int sum = 0;
#pragma unroll
    for (int i = 0; i < 64; ++i) v[i] = cnt[lane * 64 + i];
#pragma unroll
    for (int i = 0; i < 64; ++i) { int x = v[i]; v[i] = sum; sum += x; }
    // exclusive wave-scan of per-lane sums
    int incl = sum;
#pragma unroll
    for (int d = 1; d < 64; d <<= 1) {
        int o = __shfl_up(incl, d);
        if (lane >= d) incl += o;
    }
    int excl = incl - sum;
#pragma unroll
    for (int i = 0; i < 64; ++i) cnt[lane * 64 + i] = v[i] + excl;
}

// --- K4: scatter tokens into vocab-sorted pair array; cnt doubles as cursor ---
__global__ __launch_bounds__(256) void scatter_kernel(const int* __restrict__ tokens,
                                                      int* __restrict__ cursor,
                                                      unsigned* __restrict__ pairs) {
    int t = blockIdx.x * 256 + threadIdx.x;
    int tok = tokens[t];
    int pos = atomicAdd(&cursor[tok >> 4], 1);
    pairs[pos] = ((unsigned)t << 16) | (unsigned)tok;   // t<2^14, tok<2^16
}

// --- K5: main gather in sorted order ---
constexpr int E4     = E / 4;                 // 192
constexpr int TOTAL5 = NTOK * E4;             // 3,145,728 threads
constexpr int GRID5  = TOTAL5 / 256;          // 12288 blocks (divisible by 8)
constexpr int CPX    = GRID5 / 8;             // 1536 blocks per XCD chunk

__global__ __launch_bounds__(256) void gather_sorted_kernel(
    const unsigned* __restrict__ pairs,
    const float*    __restrict__ W,
    const float*    __restrict__ bias,
    float*          __restrict__ out)
{
    // XCD-chunked swizzle: XCD x (= bid%8) gets contiguous logical range
    int bid = blockIdx.x;
    int lb  = (bid & 7) * CPX + (bid >> 3);
    int g   = lb * 256 + threadIdx.x;

    int m = g / E4;            // sorted match index (wave-uniform: 64 | 192*k)
    int j = g - m * E4;        // float4 group within the embedding row

    unsigned pr = pairs[m];
    int t   = (int)(pr >> 16);
    int tok = (int)(pr & 0xFFFFu);

    const float* wp = W + (size_t)(4 * j) * V + tok;
    f32x4 r;
    r.x = wp[0 * (size_t)V];
    r.y = wp[1 * (size_t)V];
    r.z = wp[2 * (size_t)V];
    r.w = wp[3 * (size_t)V];
    r += ((const f32x4*)bias)[j];

    // nontemporal: out is write-once; keep L2 for W lines
    __builtin_nontemporal_store(r, (f32x4*)out + (size_t)t * E4 + j);
}

extern "C" void kernel_launch(void* const* d_in, const int* in_sizes, int n_in,
                              void* d_out, int out_size, void* d_ws, size_t ws_size,
                              hipStream_t stream) {
    const int*   tokens = (const int*)  d_in[0];
    const float* W      = (const float*)d_in[1];
    const float* bias   = (const float*)d_in[2];
    float*       out    = (float*)      d_out;

    int*      cnt   = (int*)d_ws;                  // [4096]
    unsigned* pairs = (unsigned*)((char*)d_ws + NBP * sizeof(int));  // [16384]

    hipMemsetAsync(cnt, 0, NBP * sizeof(int), stream);
    hist_kernel   <<<NTOK / 256, 256, 0, stream>>>(tokens, cnt);
    scan_kernel   <<<1, 64, 0, stream>>>(cnt);
    scatter_kernel<<<NTOK / 256, 256, 0, stream>>>(tokens, cnt, pairs);
    gather_sorted_kernel<<<GRID5, 256, 0, stream>>>(pairs, W, bias, out);
}

// Round 4
// 250.880 us; speedup vs baseline: 1.6639x; 1.0952x over previous
//
#include <hip/hip_runtime.h>

// Embedding gather: out[b,t,:] = W[:, tokens[b,t]] + bias
//   tokens: [16384] int32, W: [768, 50257] f32 row-major, bias: [768], out: [16384, 768]
//
// R2: arrival-order gather → 766 MB HBM (5x dup).  R3: vocab-sorted order →
// 76 MB HBM but 97 us: each wave instr touched 64 distinct lines (lanes across
// e-rows) → 12.6M line requests, L2-missing → L3-request-rate bound.
// R4 (this): lanes across 64 CONSECUTIVE SORTED MATCHES at fixed e-row →
// ~13 lines/instr (sorted tokens ~3 apart).  64x192 tile transposed via LDS
// (pad 193 → conflict-free both phases), coalesced row-wise writes.
//
// ws: [0,4096) int32 bucket counters/offsets/cursors; [4096,+16384) packed pairs.

constexpr int V     = 50257;
constexpr int E     = 768;
constexpr int NTOK  = 8 * 2048;          // 16384
constexpr int NBP   = 4096;              // padded bucket count (tok>>4 buckets)

typedef float f32x4 __attribute__((ext_vector_type(4)));

// --- K1: histogram tokens into buckets (cnt pre-zeroed by memset) ---
__global__ __launch_bounds__(256) void hist_kernel(const int* __restrict__ tokens,
                                                   int* __restrict__ cnt) {
    int t = blockIdx.x * 256 + threadIdx.x;
    atomicAdd(&cnt[tokens[t] >> 4], 1);
}

// --- K2: exclusive prefix scan of cnt[4096] in-place, single wave ---
__global__ __launch_bounds__(64) void scan_kernel(int* __restrict__ cnt) {
    int lane = threadIdx.x;
    int v[64];
    int sum = 0;
#pragma unroll
    for (int i = 0; i < 64; ++i) v[i] = cnt[lane * 64 + i];
#pragma unroll
    for (int i = 0; i < 64; ++i) { int x = v[i]; v[i] = sum; sum += x; }
    int incl = sum;
#pragma unroll
    for (int d = 1; d < 64; d <<= 1) {
        int o = __shfl_up(incl, d);
        if (lane >= d) incl += o;
    }
    int excl = incl - sum;
#pragma unroll
    for (int i = 0; i < 64; ++i) cnt[lane * 64 + i] = v[i] + excl;
}

// --- K3: scatter tokens into vocab-sorted pair array; cnt doubles as cursor ---
__global__ __launch_bounds__(256) void scatter_kernel(const int* __restrict__ tokens,
                                                      int* __restrict__ cursor,
                                                      unsigned* __restrict__ pairs) {
    int t = blockIdx.x * 256 + threadIdx.x;
    int tok = tokens[t];
    int pos = atomicAdd(&cursor[tok >> 4], 1);
    pairs[pos] = ((unsigned)t << 16) | (unsigned)tok;   // t<2^14, tok<2^16
}

// --- K4: transposed gather ---
constexpr int MB   = 64;                 // sorted matches per block (= lane dim)
constexpr int EC   = 192;                // e-dims per block
constexpr int EPW  = EC / 4;             // 48 e-rows per wave
constexpr int NMB  = NTOK / MB;          // 256
constexpr int NEB  = E / EC;             // 4
constexpr int GRID = NMB * NEB;          // 1024 blocks
constexpr int CPX  = GRID / 8;           // 128 blocks per XCD chunk
constexpr int PAD  = EC + 1;             // 193: bank = (lane + e) % 32 → 2-way (free)

__global__ __launch_bounds__(256) void gather_t_kernel(
    const unsigned* __restrict__ pairs,
    const float*    __restrict__ W,
    const float*    __restrict__ bias,
    float*          __restrict__ out)
{
    __shared__ float    lds[MB * PAD];
    __shared__ unsigned prs[MB];

    // XCD-chunked swizzle; within a chunk, e-chunk fastest so consecutive
    // logical blocks share sorted-m boundary lines on the same XCD L2.
    int bid = blockIdx.x;
    int lb  = (bid & 7) * CPX + (bid >> 3);
    int mblk = lb / NEB, eblk = lb % NEB;
    int m0 = mblk * MB, e0 = eblk * EC;

    int tid = threadIdx.x, lane = tid & 63, w = tid >> 6;
    if (tid < MB) prs[tid] = pairs[m0 + tid];
    __syncthreads();

    int tok = (int)(prs[lane] & 0xFFFFu);

    // read phase: wave w owns e_local = w*48 .. w*48+47; lanes = 64 sorted
    // matches → each gather instr touches ~13 cache lines (sorted spacing ~3).
    const float* wp = W + (size_t)(e0 + w * EPW) * V + tok;
#pragma unroll
    for (int i = 0; i < EPW; ++i) {
        float v = wp[(size_t)i * V] + bias[e0 + w * EPW + i];
        lds[lane * PAD + w * EPW + i] = v;
    }
    __syncthreads();

    // write phase: wave w owns rows w*16..w*16+15; row uniform per instr,
    // 64 consecutive f32 per store → fully coalesced.
#pragma unroll
    for (int r8 = 0; r8 < 16; ++r8) {
        int r = w * 16 + r8;
        int t = (int)(prs[r] >> 16);
        float* orow = out + (size_t)t * E + e0;
#pragma unroll
        for (int c = 0; c < 3; ++c) {
            float v = lds[r * PAD + c * 64 + lane];
            __builtin_nontemporal_store(v, orow + c * 64 + lane);
        }
    }
}

extern "C" void kernel_launch(void* const* d_in, const int* in_sizes, int n_in,
                              void* d_out, int out_size, void* d_ws, size_t ws_size,
                              hipStream_t stream) {
    const int*   tokens = (const int*)  d_in[0];
    const float* W      = (const float*)d_in[1];
    const float* bias   = (const float*)d_in[2];
    float*       out    = (float*)      d_out;

    int*      cnt   = (int*)d_ws;                                    // [4096]
    unsigned* pairs = (unsigned*)((char*)d_ws + NBP * sizeof(int));  // [16384]

    hipMemsetAsync(cnt, 0, NBP * sizeof(int), stream);
    hist_kernel   <<<NTOK / 256, 256, 0, stream>>>(tokens, cnt);
    scan_kernel   <<<1, 64, 0, stream>>>(cnt);
    scatter_kernel<<<NTOK / 256, 256, 0, stream>>>(tokens, cnt, pairs);
    gather_t_kernel<<<GRID, 256, 0, stream>>>(pairs, W, bias, out);
}